// Round 13
// baseline (253.915 us; speedup 1.0000x reference)
//
#include <hip/hip_runtime.h>
#include <hip/hip_bf16.h>

#define N_NODES 50000
#define N_EDGES 600000
#define HID     128
#define NG      500
#define NB_SCAN 196   // ceil(50000/256)
#define EB      2345  // ceil(600000/256) + 1 extra block for w3lin
#define ECAP    1152  // LDS edge-slice capacity for 64-row tile (mean 768, sd ~28)

// ---------------- degree count + pos (+ last block computes w3lin = W3@Wlin) ----------------

__global__ void k_count(const int* __restrict__ dst, int* __restrict__ cnt,
                        int* __restrict__ pos,
                        const float* __restrict__ W3, const float* __restrict__ Wlin,
                        const float* __restrict__ b3, const float* __restrict__ blin,
                        float* __restrict__ w3buf) {
    if (blockIdx.x == EB - 1) {
        int t = threadIdx.x;          // 256 threads -> 128x2
        int k = t >> 1, j = t & 1;
        float acc = 0.f;
        for (int m = 0; m < 128; m++) acc += W3[k * 128 + m] * Wlin[m * 2 + j];
        w3buf[k * 2 + j] = acc;
        if (t < 2) {
            float c = 0.f;
            for (int m = 0; m < 128; m++) c += b3[m] * Wlin[m * 2 + t];
            w3buf[256 + t] = c + blin[t];   // const added to every non-empty graph
            w3buf[258 + t] = blin[t];       // empty-graph fallback
        }
        return;
    }
    int e = blockIdx.x * 256 + threadIdx.x;
    if (e < N_EDGES) pos[e] = atomicAdd(&cnt[dst[e]], 1);
}

__global__ void k_blocksum(const int* __restrict__ cnt, int* __restrict__ bsum) {
    __shared__ int s[256];
    int i = blockIdx.x * 256 + threadIdx.x;
    s[threadIdx.x] = (i < N_NODES) ? cnt[i] : 0;
    __syncthreads();
    for (int o = 128; o; o >>= 1) {
        if (threadIdx.x < o) s[threadIdx.x] += s[threadIdx.x + o];
        __syncthreads();
    }
    if (threadIdx.x == 0) bsum[blockIdx.x] = s[0];
}

// rowptr + dinv + xd; per-block bsum prefix computed in-kernel
__global__ void k_rowptr(const int* __restrict__ cnt, const int* __restrict__ bsum,
                         const float* __restrict__ x,
                         int* __restrict__ rowptr, float* __restrict__ dinv,
                         float* __restrict__ xd) {
    __shared__ int s[256];
    __shared__ int base_sh;
    int v = (threadIdx.x < (int)blockIdx.x && threadIdx.x < NB_SCAN) ? bsum[threadIdx.x] : 0;
    s[threadIdx.x] = v;
    __syncthreads();
    for (int o = 128; o; o >>= 1) {
        if (threadIdx.x < o) s[threadIdx.x] += s[threadIdx.x + o];
        __syncthreads();
    }
    if (threadIdx.x == 0) base_sh = s[0];
    __syncthreads();
    int base = base_sh;
    __syncthreads();

    int i = blockIdx.x * 256 + threadIdx.x;
    int c = (i < N_NODES) ? cnt[i] : 0;
    s[threadIdx.x] = c;
    __syncthreads();
    for (int o = 1; o < 256; o <<= 1) {
        int vv = (threadIdx.x >= o) ? s[threadIdx.x - o] : 0;
        __syncthreads();
        s[threadIdx.x] += vv;
        __syncthreads();
    }
    if (i < N_NODES) {
        int incl = s[threadIdx.x];
        rowptr[i] = base + incl - c;
        float di = rsqrtf((float)c + 1.0f);
        dinv[i] = di;
        xd[i] = x[i] * di;
        if (i == N_NODES - 1) rowptr[N_NODES] = base + incl;
    }
}

// CSR fill — no atomics, independent per edge
__global__ void k_fill(const int* __restrict__ src, const int* __restrict__ dst,
                       const int* __restrict__ rowptr, const int* __restrict__ pos,
                       int* __restrict__ csr) {
    int e = blockIdx.x * 256 + threadIdx.x;
    if (e < N_EDGES) {
        int d = dst[e];
        csr[rowptr[d] + pos[e]] = src[e];
    }
}

// layer-1 scalar aggregate, 8 lanes per node: s1d[i] = {x_i*di^2 + (Σ xd[j])*di, di}
__global__ void k_s1d(const float* __restrict__ x, const float* __restrict__ xd,
                      const float* __restrict__ dinv, const int* __restrict__ rowptr,
                      const int* __restrict__ csr, float2* __restrict__ s1d) {
    int tid = blockIdx.x * 256 + threadIdx.x;
    int i = tid >> 3, sub = tid & 7;
    if (i >= N_NODES) return;
    int e0 = rowptr[i], e1 = rowptr[i + 1];
    float acc = 0.f;
    for (int e = e0 + sub; e < e1; e += 8) acc += xd[csr[e]];
    acc += __shfl_xor(acc, 1);
    acc += __shfl_xor(acc, 2);
    acc += __shfl_xor(acc, 4);
    if (sub == 0) {
        float di = dinv[i];
        float2 r = {x[i] * di * di + acc * di, di};
        s1d[i] = r;
    }
}

// ---------------- Fused: reconstruct-aggregate g=A·h1, GEMM g@W2, relu+b2, ·w3lin -> zd[N,2]
// 64-row tile. Phase A: lane(64)=row, grp(4)=32-ch chunk — sjd LDS re-reads 4x (was 8x).
// GEMM retile (R12 lesson — LDS-read-bound): 4 rows x 8 cols/thread -> each HsT b128
// feeds 32 fma; HsT LDS traffic halves to ~400MB. W2 from global (L1/L2-resident).

__global__ __launch_bounds__(256) void k_gemm_fused(const float2* __restrict__ s1d,
                                                    const int* __restrict__ rowptr,
                                                    const int* __restrict__ csr,
                                                    const float* __restrict__ W1,
                                                    const float* __restrict__ b1,
                                                    const float* __restrict__ W2,
                                                    const float* __restrict__ b2,
                                                    const float* __restrict__ w3buf,
                                                    float* __restrict__ zd) {
    __shared__ float HsT[128 * 64];   // 32 KB, [ch][row]
    __shared__ int rp_sh[65];
    __shared__ int csr_sh[ECAP];      // 4.5 KB
    __shared__ float2 sjd_sh[ECAP];   // 9 KB
    int t = threadIdx.x;
    int r0 = blockIdx.x * 64;
    int lane = t & 63, grp = t >> 6;  // lane = row, grp = 32-channel chunk (4 x 32)

    if (t < 65) {
        int i = r0 + t;
        rp_sh[t] = rowptr[(i <= N_NODES) ? i : N_NODES];
    }
    __syncthreads();
    int estart = rp_sh[0];
    int len = rp_sh[64] - estart;
    bool fast = (len <= ECAP);
    if (fast) {
        for (int i = t; i < len; i += 256) csr_sh[i] = csr[estart + i];
        __syncthreads();
        for (int i = t; i < len; i += 256) sjd_sh[i] = s1d[csr_sh[i]];
    }
    __syncthreads();

    float w1r[32], b1r[32];
    #pragma unroll
    for (int kk = 0; kk < 32; kk++) { w1r[kk] = W1[grp * 32 + kk]; b1r[kk] = b1[grp * 32 + kk]; }

    float ga[32];
    #pragma unroll
    for (int kk = 0; kk < 32; kk++) ga[kk] = 0.f;
    int node = r0 + lane;
    if (node < N_NODES) {
        float2 sd = s1d[node];
        float di = sd.y, wself = sd.y * sd.y;
        #pragma unroll
        for (int kk = 0; kk < 32; kk++) ga[kk] = fmaxf(sd.x * w1r[kk] + b1r[kk], 0.f) * wself;
        int e0 = rp_sh[lane] - estart, e1 = rp_sh[lane + 1] - estart;
        if (fast) {
            int e = e0;
            for (; e + 1 < e1; e += 2) {
                float2 s0 = sjd_sh[e], s1v = sjd_sh[e + 1];
                float wj0 = s0.y * di, wj1 = s1v.y * di;
                #pragma unroll
                for (int kk = 0; kk < 32; kk++) {
                    ga[kk] += fmaxf(s0.x  * w1r[kk] + b1r[kk], 0.f) * wj0
                            + fmaxf(s1v.x * w1r[kk] + b1r[kk], 0.f) * wj1;
                }
            }
            if (e < e1) {
                float2 sj = sjd_sh[e];
                float wj = sj.y * di;
                #pragma unroll
                for (int kk = 0; kk < 32; kk++)
                    ga[kk] += fmaxf(sj.x * w1r[kk] + b1r[kk], 0.f) * wj;
            }
        } else {   // overflow fallback (block-uniform, ~never taken)
            for (int e = e0; e < e1; e++) {
                float2 sj = s1d[csr[estart + e]];
                float wj = sj.y * di;
                #pragma unroll
                for (int kk = 0; kk < 32; kk++)
                    ga[kk] += fmaxf(sj.x * w1r[kk] + b1r[kk], 0.f) * wj;
            }
        }
    }
    #pragma unroll
    for (int kk = 0; kk < 32; kk++) HsT[(grp * 32 + kk) * 64 + lane] = ga[kk];
    __syncthreads();

    // GEMM: 64 rows x 128 cols; each thread 4 rows x 8 cols (16x16 thread grid)
    int col = (t & 15) * 8;       // 0..120
    int row = (t >> 4) * 4;       // 0..60
    float a0[4][4] = {}, a1[4][4] = {};
    #pragma unroll 2
    for (int k = 0; k < 128; k++) {
        float4 w0 = *(const float4*)&W2[k * 128 + col];
        float4 w1 = *(const float4*)&W2[k * 128 + col + 4];
        float4 h  = *(float4*)&HsT[k * 64 + row];
        a0[0][0] += h.x * w0.x; a0[0][1] += h.x * w0.y; a0[0][2] += h.x * w0.z; a0[0][3] += h.x * w0.w;
        a0[1][0] += h.y * w0.x; a0[1][1] += h.y * w0.y; a0[1][2] += h.y * w0.z; a0[1][3] += h.y * w0.w;
        a0[2][0] += h.z * w0.x; a0[2][1] += h.z * w0.y; a0[2][2] += h.z * w0.z; a0[2][3] += h.z * w0.w;
        a0[3][0] += h.w * w0.x; a0[3][1] += h.w * w0.y; a0[3][2] += h.w * w0.z; a0[3][3] += h.w * w0.w;
        a1[0][0] += h.x * w1.x; a1[0][1] += h.x * w1.y; a1[0][2] += h.x * w1.z; a1[0][3] += h.x * w1.w;
        a1[1][0] += h.y * w1.x; a1[1][1] += h.y * w1.y; a1[1][2] += h.y * w1.z; a1[1][3] += h.y * w1.w;
        a1[2][0] += h.z * w1.x; a1[2][1] += h.z * w1.y; a1[2][2] += h.z * w1.z; a1[2][3] += h.z * w1.w;
        a1[3][0] += h.w * w1.x; a1[3][1] += h.w * w1.y; a1[3][2] += h.w * w1.z; a1[3][3] += h.w * w1.w;
    }

    // epilogue: relu(+b2), project to 2 outputs, reduce across the 16 col-lanes, scale by dinv
    float b2a[4], b2b[4], wa0[4], wa1[4], wb0[4], wb1[4];
    #pragma unroll
    for (int c = 0; c < 4; c++) {
        b2a[c] = b2[col + c];          b2b[c] = b2[col + 4 + c];
        wa0[c] = w3buf[(col + c) * 2 + 0];     wa1[c] = w3buf[(col + c) * 2 + 1];
        wb0[c] = w3buf[(col + 4 + c) * 2 + 0]; wb1[c] = w3buf[(col + 4 + c) * 2 + 1];
    }
    #pragma unroll
    for (int r = 0; r < 4; r++) {
        float p0 = 0.f, p1 = 0.f;
        #pragma unroll
        for (int c = 0; c < 4; c++) {
            float v0 = fmaxf(a0[r][c] + b2a[c], 0.f);
            float v1 = fmaxf(a1[r][c] + b2b[c], 0.f);
            p0 += v0 * wa0[c] + v1 * wb0[c];
            p1 += v0 * wa1[c] + v1 * wb1[c];
        }
        for (int o = 1; o < 16; o <<= 1) { p0 += __shfl_xor(p0, o); p1 += __shfl_xor(p1, o); }
        int rg = r0 + row + r;
        if ((t & 15) == 0 && rg < N_NODES) {
            float dr = s1d[rg].y;
            zd[rg * 2 + 0] = p0 * dr;
            zd[rg * 2 + 1] = p1 * dr;
        }
    }
}

// ---------------- Layer-3 aggregation on zd (premultiplied), 8 lanes/node -> atomic pool

__global__ void k_aggz(const float* __restrict__ zd, const int* __restrict__ rowptr,
                       const int* __restrict__ csr, const float* __restrict__ dinv,
                       const int* __restrict__ batch, float* __restrict__ pool) {
    int tid = blockIdx.x * 256 + threadIdx.x;
    int i = tid >> 3, sub = tid & 7;
    if (i >= N_NODES) return;
    const float2* Z = (const float2*)zd;
    int e0 = rowptr[i], e1 = rowptr[i + 1];
    float a0 = 0.f, a1 = 0.f;
    for (int e = e0 + sub; e < e1; e += 8) {
        float2 zj = Z[csr[e]];
        a0 += zj.x; a1 += zj.y;
    }
    a0 += __shfl_xor(a0, 1); a1 += __shfl_xor(a1, 1);
    a0 += __shfl_xor(a0, 2); a1 += __shfl_xor(a1, 2);
    a0 += __shfl_xor(a0, 4); a1 += __shfl_xor(a1, 4);
    if (sub == 0) {
        float di = dinv[i];
        float2 zi = Z[i];
        float r0 = (zi.x + a0) * di;   // zd_i*di + di*Σ zd_j
        float r1 = (zi.y + a1) * di;
        int g = batch[i];
        atomicAdd(&pool[g * 2 + 0], r0);
        atomicAdd(&pool[g * 2 + 1], r1);
    }
}

// ---------------- Final: mean + consts (batch sorted; counts via binary search) ----------------

__global__ __launch_bounds__(256) void k_final3(const float* __restrict__ pool,
                                                const int* __restrict__ batch,
                                                const float* __restrict__ w3buf,
                                                float* __restrict__ out) {
    int g = blockIdx.x * 256 + threadIdx.x;
    if (g >= NG) return;
    int lo = 0, hi = N_NODES;
    while (lo < hi) { int mid = (lo + hi) >> 1; if (batch[mid] < g) lo = mid + 1; else hi = mid; }
    int start = lo;
    hi = N_NODES;
    while (lo < hi) { int mid = (lo + hi) >> 1; if (batch[mid] < g + 1) lo = mid + 1; else hi = mid; }
    int end = lo;
    if (end > start) {
        float inv = 1.0f / (float)(end - start);
        out[g * 2 + 0] = pool[g * 2 + 0] * inv + w3buf[256];
        out[g * 2 + 1] = pool[g * 2 + 1] * inv + w3buf[257];
    } else {
        out[g * 2 + 0] = w3buf[258];
        out[g * 2 + 1] = w3buf[259];
    }
}

// ---------------- launch ----------------

extern "C" void kernel_launch(void* const* d_in, const int* in_sizes, int n_in,
                              void* d_out, int out_size, void* d_ws, size_t ws_size,
                              hipStream_t stream) {
    const float* x    = (const float*)d_in[0];
    const float* W1   = (const float*)d_in[1];
    const float* b1   = (const float*)d_in[2];
    const float* W2   = (const float*)d_in[3];
    const float* b2   = (const float*)d_in[4];
    const float* W3   = (const float*)d_in[5];
    const float* b3   = (const float*)d_in[6];
    const float* Wlin = (const float*)d_in[7];
    const float* blin = (const float*)d_in[8];
    const int*   eidx = (const int*)d_in[9];
    const int*   batch= (const int*)d_in[10];
    const int* esrc = eidx;
    const int* edst = eidx + N_EDGES;
    float* out = (float*)d_out;

    char* w = (char*)d_ws;
    size_t off = 0;
    auto alloc = [&](size_t bytes) { size_t o = off; off = (off + bytes + 255) & ~(size_t)255; return o; };
    // cnt and pool adjacent -> one memset zeroes both
    size_t cnt_off = alloc(N_NODES * 4);
    int*   cnt    = (int*)  (w + cnt_off);
    float* pool   = (float*)(w + alloc(NG * 2 * 4));
    size_t zero_bytes = off - cnt_off;
    int*   rowptr = (int*)  (w + alloc((N_NODES + 1) * 4));
    int*   csr    = (int*)  (w + alloc(N_EDGES * 4));
    int*   pos    = (int*)  (w + alloc(N_EDGES * 4));
    float* dinv   = (float*)(w + alloc(N_NODES * 4));
    float* xd     = (float*)(w + alloc(N_NODES * 4));
    float2* s1d   = (float2*)(w + alloc((size_t)N_NODES * 8));
    int*   bsum   = (int*)  (w + alloc(NB_SCAN * 4));
    float* w3buf  = (float*)(w + alloc(260 * 4));
    float* zd     = (float*)(w + alloc((size_t)N_NODES * 2 * 4));

    const int FB = (N_EDGES + 255) / 256;       // 2344
    const int OB = (N_NODES * 8 + 255) / 256;   // 1563 (8 lanes/node)
    // 1: zero cnt + pool
    hipMemsetAsync(cnt, 0, zero_bytes, stream);
    // 2: degree count + pos + w3lin precompute (extra block)
    k_count<<<EB, 256, 0, stream>>>(edst, cnt, pos, W3, Wlin, b3, blin, w3buf);
    // 3: per-256-chunk sums
    k_blocksum<<<NB_SCAN, 256, 0, stream>>>(cnt, bsum);
    // 4: rowptr + dinv + xd
    k_rowptr<<<NB_SCAN, 256, 0, stream>>>(cnt, bsum, x, rowptr, dinv, xd);
    // 5: CSR fill (atomic-free)
    k_fill<<<FB, 256, 0, stream>>>(esrc, edst, rowptr, pos, csr);
    // 6: layer-1 scalar aggregate (8 lanes/node)
    k_s1d<<<OB, 256, 0, stream>>>(x, xd, dinv, rowptr, csr, s1d);
    // 7: fused reconstruct + GEMM + relu + projection -> zd [N,2]  (64-row tiles)
    k_gemm_fused<<<(N_NODES + 63) / 64, 256, 0, stream>>>(s1d, rowptr, csr,
                                                          W1, b1, W2, b2, w3buf, zd);
    // 8: layer-3 aggregation on zd (8 lanes/node) + atomic pool
    k_aggz<<<OB, 256, 0, stream>>>(zd, rowptr, csr, dinv, batch, pool);
    // 9: mean + consts
    k_final3<<<2, 256, 0, stream>>>(pool, batch, w3buf, out);
}

// Round 14
// 246.751 us; speedup vs baseline: 1.0290x; 1.0290x over previous
//
#include <hip/hip_runtime.h>
#include <hip/hip_bf16.h>

#define N_NODES 50000
#define N_EDGES 600000
#define HID     128
#define NG      500
#define NB_SCAN 196   // ceil(50000/256)
#define EB      2345  // ceil(600000/256) + 1 extra block for w3lin
#define ECAP    768   // LDS edge-slice capacity (mean 384, sd 62 -> +6 sigma)

// ---------------- degree count + pos (+ last block computes w3lin = W3@Wlin) ----------------

__global__ void k_count(const int* __restrict__ dst, int* __restrict__ cnt,
                        int* __restrict__ pos,
                        const float* __restrict__ W3, const float* __restrict__ Wlin,
                        const float* __restrict__ b3, const float* __restrict__ blin,
                        float* __restrict__ w3buf) {
    if (blockIdx.x == EB - 1) {
        int t = threadIdx.x;          // 256 threads -> 128x2
        int k = t >> 1, j = t & 1;
        float acc = 0.f;
        for (int m = 0; m < 128; m++) acc += W3[k * 128 + m] * Wlin[m * 2 + j];
        w3buf[k * 2 + j] = acc;
        if (t < 2) {
            float c = 0.f;
            for (int m = 0; m < 128; m++) c += b3[m] * Wlin[m * 2 + t];
            w3buf[256 + t] = c + blin[t];   // const added to every non-empty graph
            w3buf[258 + t] = blin[t];       // empty-graph fallback
        }
        return;
    }
    int e = blockIdx.x * 256 + threadIdx.x;
    if (e < N_EDGES) pos[e] = atomicAdd(&cnt[dst[e]], 1);
}

// rowptr + dinv + xd; chunk-prefix computed in-kernel by strided sum over cnt[0..256b)
// (k_blocksum dispatch deleted — 4.9M coalesced L2-hit reads total, ~2us aggregate)
__global__ void k_rowptr(const int* __restrict__ cnt, const float* __restrict__ x,
                         int* __restrict__ rowptr, float* __restrict__ dinv,
                         float* __restrict__ xd) {
    __shared__ int s[256];
    __shared__ int base_sh;
    int lim = blockIdx.x * 256;
    int partial = 0;
    for (int i = threadIdx.x; i < lim; i += 256) partial += cnt[i];
    s[threadIdx.x] = partial;
    __syncthreads();
    for (int o = 128; o; o >>= 1) {
        if (threadIdx.x < o) s[threadIdx.x] += s[threadIdx.x + o];
        __syncthreads();
    }
    if (threadIdx.x == 0) base_sh = s[0];
    __syncthreads();
    int base = base_sh;
    __syncthreads();

    int i = blockIdx.x * 256 + threadIdx.x;
    int c = (i < N_NODES) ? cnt[i] : 0;
    s[threadIdx.x] = c;
    __syncthreads();
    for (int o = 1; o < 256; o <<= 1) {
        int vv = (threadIdx.x >= o) ? s[threadIdx.x - o] : 0;
        __syncthreads();
        s[threadIdx.x] += vv;
        __syncthreads();
    }
    if (i < N_NODES) {
        int incl = s[threadIdx.x];
        rowptr[i] = base + incl - c;
        float di = rsqrtf((float)c + 1.0f);
        dinv[i] = di;
        xd[i] = x[i] * di;
        if (i == N_NODES - 1) rowptr[N_NODES] = base + incl;
    }
}

// CSR fill — no atomics, independent per edge
__global__ void k_fill(const int* __restrict__ src, const int* __restrict__ dst,
                       const int* __restrict__ rowptr, const int* __restrict__ pos,
                       int* __restrict__ csr) {
    int e = blockIdx.x * 256 + threadIdx.x;
    if (e < N_EDGES) {
        int d = dst[e];
        csr[rowptr[d] + pos[e]] = src[e];
    }
}

// layer-1 scalar aggregate, 4 lanes per node (R12-proven):
// s1d[i] = {x_i*di^2 + (Σ xd[j])*di, di}
__global__ void k_s1d(const float* __restrict__ x, const float* __restrict__ xd,
                      const float* __restrict__ dinv, const int* __restrict__ rowptr,
                      const int* __restrict__ csr, float2* __restrict__ s1d) {
    int tid = blockIdx.x * 256 + threadIdx.x;
    int i = tid >> 2, sub = tid & 3;
    if (i >= N_NODES) return;
    int e0 = rowptr[i], e1 = rowptr[i + 1];
    float acc = 0.f;
    for (int e = e0 + sub; e < e1; e += 4) acc += xd[csr[e]];
    acc += __shfl_xor(acc, 1);
    acc += __shfl_xor(acc, 2);
    if (sub == 0) {
        float di = dinv[i];
        float2 r = {x[i] * di * di + acc * di, di};
        s1d[i] = r;
    }
}

// ---------------- Fused: reconstruct-aggregate g=A·h1, GEMM g@W2, relu+b2, ·w3lin -> zd[N,2]
// R12-exact config (proven best: 51us): 32-row tile, 1563 blocks (~6/CU), 16KB HsT,
// 8x16-channel groups, 4r x 4c GEMM. Epilogue stores zd = z*dinv for single-gather aggz.

__global__ __launch_bounds__(256) void k_gemm_fused(const float2* __restrict__ s1d,
                                                    const int* __restrict__ rowptr,
                                                    const int* __restrict__ csr,
                                                    const float* __restrict__ W1,
                                                    const float* __restrict__ b1,
                                                    const float* __restrict__ W2,
                                                    const float* __restrict__ b2,
                                                    const float* __restrict__ w3buf,
                                                    float* __restrict__ zd,
                                                    float* __restrict__ pool) {
    __shared__ float HsT[128 * 32];   // 16 KB, [ch][r]
    __shared__ int rp_sh[33];
    __shared__ int csr_sh[ECAP];      // 3 KB
    __shared__ float2 sjd_sh[ECAP];   // 6 KB
    int t = threadIdx.x;
    int r0 = blockIdx.x * 32;
    int lane = t & 31, grp = t >> 5;  // lane = row in tile, grp = 16-channel chunk (8 x 16)

    // block 0 zeroes the 4KB pool (runs strictly before k_aggz)
    if (blockIdx.x == 0 && t < NG * 2 / 2) ((float2*)pool)[t] = make_float2(0.f, 0.f);

    if (t < 33) {
        int i = r0 + t;
        rp_sh[t] = rowptr[(i <= N_NODES) ? i : N_NODES];
    }
    __syncthreads();
    int estart = rp_sh[0];
    int len = rp_sh[32] - estart;
    bool fast = (len <= ECAP);
    if (fast) {
        for (int i = t; i < len; i += 256) csr_sh[i] = csr[estart + i];
        __syncthreads();
        for (int i = t; i < len; i += 256) sjd_sh[i] = s1d[csr_sh[i]];
    }
    __syncthreads();

    float w1r[16], b1r[16];
    #pragma unroll
    for (int kk = 0; kk < 16; kk++) { w1r[kk] = W1[grp * 16 + kk]; b1r[kk] = b1[grp * 16 + kk]; }

    float ga[16];
    #pragma unroll
    for (int kk = 0; kk < 16; kk++) ga[kk] = 0.f;
    int node = r0 + lane;
    if (node < N_NODES) {
        float2 sd = s1d[node];
        float di = sd.y, wself = sd.y * sd.y;
        #pragma unroll
        for (int kk = 0; kk < 16; kk++) ga[kk] = fmaxf(sd.x * w1r[kk] + b1r[kk], 0.f) * wself;
        int e0 = rp_sh[lane] - estart, e1 = rp_sh[lane + 1] - estart;
        if (fast) {
            int e = e0;
            for (; e + 3 < e1; e += 4) {
                float2 s0 = sjd_sh[e], s1v = sjd_sh[e+1], s2 = sjd_sh[e+2], s3 = sjd_sh[e+3];
                float wj0 = s0.y * di, wj1 = s1v.y * di, wj2 = s2.y * di, wj3 = s3.y * di;
                #pragma unroll
                for (int kk = 0; kk < 16; kk++) {
                    ga[kk] += fmaxf(s0.x  * w1r[kk] + b1r[kk], 0.f) * wj0
                            + fmaxf(s1v.x * w1r[kk] + b1r[kk], 0.f) * wj1
                            + fmaxf(s2.x  * w1r[kk] + b1r[kk], 0.f) * wj2
                            + fmaxf(s3.x  * w1r[kk] + b1r[kk], 0.f) * wj3;
                }
            }
            for (; e < e1; e++) {
                float2 sj = sjd_sh[e];
                float wj = sj.y * di;
                #pragma unroll
                for (int kk = 0; kk < 16; kk++)
                    ga[kk] += fmaxf(sj.x * w1r[kk] + b1r[kk], 0.f) * wj;
            }
        } else {   // overflow fallback (block-uniform, ~never taken)
            for (int e = e0; e < e1; e++) {
                float2 sj = s1d[csr[estart + e]];
                float wj = sj.y * di;
                #pragma unroll
                for (int kk = 0; kk < 16; kk++)
                    ga[kk] += fmaxf(sj.x * w1r[kk] + b1r[kk], 0.f) * wj;
            }
        }
    }
    #pragma unroll
    for (int kk = 0; kk < 16; kk++) HsT[(grp * 16 + kk) * 32 + lane] = ga[kk];
    __syncthreads();

    // GEMM: 32 rows x 128 cols; each thread 4 rows x 4 cols
    int col = (t & 31) * 4;       // 0..124
    int row = (t >> 5) * 4;       // 0..28
    float a[4][4] = {};
    #pragma unroll 4
    for (int k = 0; k < 128; k++) {
        float4 w = *(const float4*)&W2[k * 128 + col];
        float4 h = *(float4*)&HsT[k * 32 + row];
        a[0][0] += h.x * w.x; a[0][1] += h.x * w.y; a[0][2] += h.x * w.z; a[0][3] += h.x * w.w;
        a[1][0] += h.y * w.x; a[1][1] += h.y * w.y; a[1][2] += h.y * w.z; a[1][3] += h.y * w.w;
        a[2][0] += h.z * w.x; a[2][1] += h.z * w.y; a[2][2] += h.z * w.z; a[2][3] += h.z * w.w;
        a[3][0] += h.w * w.x; a[3][1] += h.w * w.y; a[3][2] += h.w * w.z; a[3][3] += h.w * w.w;
    }

    // epilogue: relu(+b2), project to 2 outputs, reduce across 32 lanes, scale by dinv
    float b2r[4], w0r[4], w1rr[4];
    #pragma unroll
    for (int c = 0; c < 4; c++) {
        b2r[c] = b2[col + c];
        w0r[c] = w3buf[(col + c) * 2 + 0];
        w1rr[c] = w3buf[(col + c) * 2 + 1];
    }
    #pragma unroll
    for (int r = 0; r < 4; r++) {
        float p0 = 0.f, p1 = 0.f;
        #pragma unroll
        for (int c = 0; c < 4; c++) {
            float v0 = fmaxf(a[r][c] + b2r[c], 0.f);
            p0 += v0 * w0r[c];
            p1 += v0 * w1rr[c];
        }
        for (int o = 1; o < 32; o <<= 1) { p0 += __shfl_xor(p0, o); p1 += __shfl_xor(p1, o); }
        int rg = r0 + row + r;
        if ((t & 31) == 0 && rg < N_NODES) {
            float dr = s1d[rg].y;
            zd[rg * 2 + 0] = p0 * dr;
            zd[rg * 2 + 1] = p1 * dr;
        }
    }
}

// ---------------- Layer-3 aggregation on zd (premultiplied), 4 lanes/node -> atomic pool

__global__ void k_aggz(const float* __restrict__ zd, const int* __restrict__ rowptr,
                       const int* __restrict__ csr, const float* __restrict__ dinv,
                       const int* __restrict__ batch, float* __restrict__ pool) {
    int tid = blockIdx.x * 256 + threadIdx.x;
    int i = tid >> 2, sub = tid & 3;
    if (i >= N_NODES) return;
    const float2* Z = (const float2*)zd;
    int e0 = rowptr[i], e1 = rowptr[i + 1];
    float a0 = 0.f, a1 = 0.f;
    for (int e = e0 + sub; e < e1; e += 4) {
        float2 zj = Z[csr[e]];
        a0 += zj.x; a1 += zj.y;
    }
    a0 += __shfl_xor(a0, 1); a1 += __shfl_xor(a1, 1);
    a0 += __shfl_xor(a0, 2); a1 += __shfl_xor(a1, 2);
    if (sub == 0) {
        float di = dinv[i];
        float2 zi = Z[i];
        float r0 = (zi.x + a0) * di;   // zd_i*di + di*Σ zd_j
        float r1 = (zi.y + a1) * di;
        int g = batch[i];
        atomicAdd(&pool[g * 2 + 0], r0);
        atomicAdd(&pool[g * 2 + 1], r1);
    }
}

// ---------------- Final: mean + consts (batch sorted; counts via binary search) ----------------

__global__ __launch_bounds__(256) void k_final3(const float* __restrict__ pool,
                                                const int* __restrict__ batch,
                                                const float* __restrict__ w3buf,
                                                float* __restrict__ out) {
    int g = blockIdx.x * 256 + threadIdx.x;
    if (g >= NG) return;
    int lo = 0, hi = N_NODES;
    while (lo < hi) { int mid = (lo + hi) >> 1; if (batch[mid] < g) lo = mid + 1; else hi = mid; }
    int start = lo;
    hi = N_NODES;
    while (lo < hi) { int mid = (lo + hi) >> 1; if (batch[mid] < g + 1) lo = mid + 1; else hi = mid; }
    int end = lo;
    if (end > start) {
        float inv = 1.0f / (float)(end - start);
        out[g * 2 + 0] = pool[g * 2 + 0] * inv + w3buf[256];
        out[g * 2 + 1] = pool[g * 2 + 1] * inv + w3buf[257];
    } else {
        out[g * 2 + 0] = w3buf[258];
        out[g * 2 + 1] = w3buf[259];
    }
}

// ---------------- launch ----------------

extern "C" void kernel_launch(void* const* d_in, const int* in_sizes, int n_in,
                              void* d_out, int out_size, void* d_ws, size_t ws_size,
                              hipStream_t stream) {
    const float* x    = (const float*)d_in[0];
    const float* W1   = (const float*)d_in[1];
    const float* b1   = (const float*)d_in[2];
    const float* W2   = (const float*)d_in[3];
    const float* b2   = (const float*)d_in[4];
    const float* W3   = (const float*)d_in[5];
    const float* b3   = (const float*)d_in[6];
    const float* Wlin = (const float*)d_in[7];
    const float* blin = (const float*)d_in[8];
    const int*   eidx = (const int*)d_in[9];
    const int*   batch= (const int*)d_in[10];
    const int* esrc = eidx;
    const int* edst = eidx + N_EDGES;
    float* out = (float*)d_out;

    char* w = (char*)d_ws;
    size_t off = 0;
    auto alloc = [&](size_t bytes) { size_t o = off; off = (off + bytes + 255) & ~(size_t)255; return o; };
    int*   cnt    = (int*)  (w + alloc(N_NODES * 4));
    float* pool   = (float*)(w + alloc(NG * 2 * 4));
    int*   rowptr = (int*)  (w + alloc((N_NODES + 1) * 4));
    int*   csr    = (int*)  (w + alloc(N_EDGES * 4));
    int*   pos    = (int*)  (w + alloc(N_EDGES * 4));
    float* dinv   = (float*)(w + alloc(N_NODES * 4));
    float* xd     = (float*)(w + alloc(N_NODES * 4));
    float2* s1d   = (float2*)(w + alloc((size_t)N_NODES * 8));
    float* w3buf  = (float*)(w + alloc(260 * 4));
    float* zd     = (float*)(w + alloc((size_t)N_NODES * 2 * 4));

    const int FB = (N_EDGES + 255) / 256;       // 2344
    const int QB = (N_NODES * 4 + 255) / 256;   // 782 (4 lanes/node)
    // 1: zero cnt
    hipMemsetAsync(cnt, 0, N_NODES * 4, stream);
    // 2: degree count + pos + w3lin precompute (extra block)
    k_count<<<EB, 256, 0, stream>>>(edst, cnt, pos, W3, Wlin, b3, blin, w3buf);
    // 3: rowptr + dinv + xd (chunk prefix computed in-kernel; k_blocksum deleted)
    k_rowptr<<<NB_SCAN, 256, 0, stream>>>(cnt, x, rowptr, dinv, xd);
    // 4: CSR fill (atomic-free)
    k_fill<<<FB, 256, 0, stream>>>(esrc, edst, rowptr, pos, csr);
    // 5: layer-1 scalar aggregate (4 lanes/node)
    k_s1d<<<QB, 256, 0, stream>>>(x, xd, dinv, rowptr, csr, s1d);
    // 6: fused reconstruct + GEMM + relu + projection -> zd [N,2]  (R12 config; zeroes pool)
    k_gemm_fused<<<(N_NODES + 31) / 32, 256, 0, stream>>>(s1d, rowptr, csr,
                                                          W1, b1, W2, b2, w3buf, zd, pool);
    // 7: layer-3 aggregation on zd (4 lanes/node) + atomic pool
    k_aggz<<<QB, 256, 0, stream>>>(zd, rowptr, csr, dinv, batch, pool);
    // 8: mean + consts
    k_final3<<<2, 256, 0, stream>>>(pool, batch, w3buf, out);
}

// Round 15
// 209.962 us; speedup vs baseline: 1.2093x; 1.1752x over previous
//
#include <hip/hip_runtime.h>
#include <hip/hip_bf16.h>

#define N_NODES 50000
#define N_EDGES 600000
#define HID     128
#define NG      500
#define NB_SCAN 196   // ceil(50000/256)
#define EB      2345  // ceil(600000/256) + 1 extra block for w3lin
#define ECAP    768   // LDS edge-slice capacity (mean 384, sd 62 -> +6 sigma)

// ---------------- degree count + pos (+ last block computes w3lin = W3@Wlin) ----------------

__global__ void k_count(const int* __restrict__ dst, int* __restrict__ cnt,
                        int* __restrict__ pos,
                        const float* __restrict__ W3, const float* __restrict__ Wlin,
                        const float* __restrict__ b3, const float* __restrict__ blin,
                        float* __restrict__ w3buf) {
    if (blockIdx.x == EB - 1) {
        int t = threadIdx.x;          // 256 threads -> 128x2
        int k = t >> 1, j = t & 1;
        float acc = 0.f;
        for (int m = 0; m < 128; m++) acc += W3[k * 128 + m] * Wlin[m * 2 + j];
        w3buf[k * 2 + j] = acc;
        if (t < 2) {
            float c = 0.f;
            for (int m = 0; m < 128; m++) c += b3[m] * Wlin[m * 2 + t];
            w3buf[256 + t] = c + blin[t];   // const added to every non-empty graph
            w3buf[258 + t] = blin[t];       // empty-graph fallback
        }
        return;
    }
    int e = blockIdx.x * 256 + threadIdx.x;
    if (e < N_EDGES) pos[e] = atomicAdd(&cnt[dst[e]], 1);
}

// rowptr + dinv + xd; chunk-prefix computed in-kernel by strided sum over cnt[0..256b)
__global__ void k_rowptr(const int* __restrict__ cnt, const float* __restrict__ x,
                         int* __restrict__ rowptr, float* __restrict__ dinv,
                         float* __restrict__ xd) {
    __shared__ int s[256];
    __shared__ int base_sh;
    int lim = blockIdx.x * 256;
    int partial = 0;
    for (int i = threadIdx.x; i < lim; i += 256) partial += cnt[i];
    s[threadIdx.x] = partial;
    __syncthreads();
    for (int o = 128; o; o >>= 1) {
        if (threadIdx.x < o) s[threadIdx.x] += s[threadIdx.x + o];
        __syncthreads();
    }
    if (threadIdx.x == 0) base_sh = s[0];
    __syncthreads();
    int base = base_sh;
    __syncthreads();

    int i = blockIdx.x * 256 + threadIdx.x;
    int c = (i < N_NODES) ? cnt[i] : 0;
    s[threadIdx.x] = c;
    __syncthreads();
    for (int o = 1; o < 256; o <<= 1) {
        int vv = (threadIdx.x >= o) ? s[threadIdx.x - o] : 0;
        __syncthreads();
        s[threadIdx.x] += vv;
        __syncthreads();
    }
    if (i < N_NODES) {
        int incl = s[threadIdx.x];
        rowptr[i] = base + incl - c;
        float di = rsqrtf((float)c + 1.0f);
        dinv[i] = di;
        xd[i] = x[i] * di;
        if (i == N_NODES - 1) rowptr[N_NODES] = base + incl;
    }
}

// CSR fill — no atomics, independent per edge
__global__ void k_fill(const int* __restrict__ src, const int* __restrict__ dst,
                       const int* __restrict__ rowptr, const int* __restrict__ pos,
                       int* __restrict__ csr) {
    int e = blockIdx.x * 256 + threadIdx.x;
    if (e < N_EDGES) {
        int d = dst[e];
        csr[rowptr[d] + pos[e]] = src[e];
    }
}

// layer-1 scalar aggregate, 4 lanes per node: s1d[i] = {x_i*di^2 + (Σ xd[j])*di, di}
__global__ void k_s1d(const float* __restrict__ x, const float* __restrict__ xd,
                      const float* __restrict__ dinv, const int* __restrict__ rowptr,
                      const int* __restrict__ csr, float2* __restrict__ s1d) {
    int tid = blockIdx.x * 256 + threadIdx.x;
    int i = tid >> 2, sub = tid & 3;
    if (i >= N_NODES) return;
    int e0 = rowptr[i], e1 = rowptr[i + 1];
    float acc = 0.f;
    for (int e = e0 + sub; e < e1; e += 4) acc += xd[csr[e]];
    acc += __shfl_xor(acc, 1);
    acc += __shfl_xor(acc, 2);
    if (sub == 0) {
        float di = dinv[i];
        float2 r = {x[i] * di * di + acc * di, di};
        s1d[i] = r;
    }
}

// ---------------- Fused: reconstruct-aggregate g=A·h1, GEMM g@W2, relu+b2, ·w3lin -> zd[N,2]
// R12-proven config: 32-row tile, 1563 blocks (~6/CU), 16KB HsT, 8x16-ch groups, 4r x 4c GEMM.
// Epilogue stores zd = z*dinv so layer-3 needs a single gather per edge.

__global__ __launch_bounds__(256) void k_gemm_fused(const float2* __restrict__ s1d,
                                                    const int* __restrict__ rowptr,
                                                    const int* __restrict__ csr,
                                                    const float* __restrict__ W1,
                                                    const float* __restrict__ b1,
                                                    const float* __restrict__ W2,
                                                    const float* __restrict__ b2,
                                                    const float* __restrict__ w3buf,
                                                    float* __restrict__ zd) {
    __shared__ float HsT[128 * 32];   // 16 KB, [ch][r]
    __shared__ int rp_sh[33];
    __shared__ int csr_sh[ECAP];      // 3 KB
    __shared__ float2 sjd_sh[ECAP];   // 6 KB
    int t = threadIdx.x;
    int r0 = blockIdx.x * 32;
    int lane = t & 31, grp = t >> 5;  // lane = row in tile, grp = 16-channel chunk (8 x 16)

    if (t < 33) {
        int i = r0 + t;
        rp_sh[t] = rowptr[(i <= N_NODES) ? i : N_NODES];
    }
    __syncthreads();
    int estart = rp_sh[0];
    int len = rp_sh[32] - estart;
    bool fast = (len <= ECAP);
    if (fast) {
        for (int i = t; i < len; i += 256) csr_sh[i] = csr[estart + i];
        __syncthreads();
        for (int i = t; i < len; i += 256) sjd_sh[i] = s1d[csr_sh[i]];
    }
    __syncthreads();

    float w1r[16], b1r[16];
    #pragma unroll
    for (int kk = 0; kk < 16; kk++) { w1r[kk] = W1[grp * 16 + kk]; b1r[kk] = b1[grp * 16 + kk]; }

    float ga[16];
    #pragma unroll
    for (int kk = 0; kk < 16; kk++) ga[kk] = 0.f;
    int node = r0 + lane;
    if (node < N_NODES) {
        float2 sd = s1d[node];
        float di = sd.y, wself = sd.y * sd.y;
        #pragma unroll
        for (int kk = 0; kk < 16; kk++) ga[kk] = fmaxf(sd.x * w1r[kk] + b1r[kk], 0.f) * wself;
        int e0 = rp_sh[lane] - estart, e1 = rp_sh[lane + 1] - estart;
        if (fast) {
            int e = e0;
            for (; e + 3 < e1; e += 4) {
                float2 s0 = sjd_sh[e], s1v = sjd_sh[e+1], s2 = sjd_sh[e+2], s3 = sjd_sh[e+3];
                float wj0 = s0.y * di, wj1 = s1v.y * di, wj2 = s2.y * di, wj3 = s3.y * di;
                #pragma unroll
                for (int kk = 0; kk < 16; kk++) {
                    ga[kk] += fmaxf(s0.x  * w1r[kk] + b1r[kk], 0.f) * wj0
                            + fmaxf(s1v.x * w1r[kk] + b1r[kk], 0.f) * wj1
                            + fmaxf(s2.x  * w1r[kk] + b1r[kk], 0.f) * wj2
                            + fmaxf(s3.x  * w1r[kk] + b1r[kk], 0.f) * wj3;
                }
            }
            for (; e < e1; e++) {
                float2 sj = sjd_sh[e];
                float wj = sj.y * di;
                #pragma unroll
                for (int kk = 0; kk < 16; kk++)
                    ga[kk] += fmaxf(sj.x * w1r[kk] + b1r[kk], 0.f) * wj;
            }
        } else {   // overflow fallback (block-uniform, ~never taken)
            for (int e = e0; e < e1; e++) {
                float2 sj = s1d[csr[estart + e]];
                float wj = sj.y * di;
                #pragma unroll
                for (int kk = 0; kk < 16; kk++)
                    ga[kk] += fmaxf(sj.x * w1r[kk] + b1r[kk], 0.f) * wj;
            }
        }
    }
    #pragma unroll
    for (int kk = 0; kk < 16; kk++) HsT[(grp * 16 + kk) * 32 + lane] = ga[kk];
    __syncthreads();

    // GEMM: 32 rows x 128 cols; each thread 4 rows x 4 cols
    int col = (t & 31) * 4;       // 0..124
    int row = (t >> 5) * 4;       // 0..28
    float a[4][4] = {};
    #pragma unroll 4
    for (int k = 0; k < 128; k++) {
        float4 w = *(const float4*)&W2[k * 128 + col];
        float4 h = *(float4*)&HsT[k * 32 + row];
        a[0][0] += h.x * w.x; a[0][1] += h.x * w.y; a[0][2] += h.x * w.z; a[0][3] += h.x * w.w;
        a[1][0] += h.y * w.x; a[1][1] += h.y * w.y; a[1][2] += h.y * w.z; a[1][3] += h.y * w.w;
        a[2][0] += h.z * w.x; a[2][1] += h.z * w.y; a[2][2] += h.z * w.z; a[2][3] += h.z * w.w;
        a[3][0] += h.w * w.x; a[3][1] += h.w * w.y; a[3][2] += h.w * w.z; a[3][3] += h.w * w.w;
    }

    // epilogue: relu(+b2), project to 2 outputs, reduce across 32 lanes, scale by dinv
    float b2r[4], w0r[4], w1rr[4];
    #pragma unroll
    for (int c = 0; c < 4; c++) {
        b2r[c] = b2[col + c];
        w0r[c] = w3buf[(col + c) * 2 + 0];
        w1rr[c] = w3buf[(col + c) * 2 + 1];
    }
    #pragma unroll
    for (int r = 0; r < 4; r++) {
        float p0 = 0.f, p1 = 0.f;
        #pragma unroll
        for (int c = 0; c < 4; c++) {
            float v0 = fmaxf(a[r][c] + b2r[c], 0.f);
            p0 += v0 * w0r[c];
            p1 += v0 * w1rr[c];
        }
        for (int o = 1; o < 32; o <<= 1) { p0 += __shfl_xor(p0, o); p1 += __shfl_xor(p1, o); }
        int rg = r0 + row + r;
        if ((t & 31) == 0 && rg < N_NODES) {
            float dr = s1d[rg].y;
            zd[rg * 2 + 0] = p0 * dr;
            zd[rg * 2 + 1] = p1 * dr;
        }
    }
}

// ---------------- Layer-3 aggregation on zd, 4 lanes/node -> plain az store (NO atomics;
// R14 lesson: the 100k-atomic pool serialization was ~48us, not the gathers)

__global__ void k_aggz(const float* __restrict__ zd, const int* __restrict__ rowptr,
                       const int* __restrict__ csr, const float* __restrict__ dinv,
                       float2* __restrict__ az) {
    int tid = blockIdx.x * 256 + threadIdx.x;
    int i = tid >> 2, sub = tid & 3;
    if (i >= N_NODES) return;
    const float2* Z = (const float2*)zd;
    int e0 = rowptr[i], e1 = rowptr[i + 1];
    float a0 = 0.f, a1 = 0.f;
    for (int e = e0 + sub; e < e1; e += 4) {
        float2 zj = Z[csr[e]];
        a0 += zj.x; a1 += zj.y;
    }
    a0 += __shfl_xor(a0, 1); a1 += __shfl_xor(a1, 1);
    a0 += __shfl_xor(a0, 2); a1 += __shfl_xor(a1, 2);
    if (sub == 0) {
        float di = dinv[i];
        float2 zi = Z[i];
        float2 r = {(zi.x + a0) * di, (zi.y + a1) * di};   // zd_i*di + di*Σ zd_j
        az[i] = r;
    }
}

// ---------------- Final: one wave per graph — segment sum of az + mean + consts ----------------

__global__ __launch_bounds__(64) void k_final(const float2* __restrict__ az,
                                              const int* __restrict__ batch,
                                              const float* __restrict__ w3buf,
                                              float* __restrict__ out) {
    int g = blockIdx.x;
    int lane = threadIdx.x;
    int lo = 0, hi = N_NODES;
    while (lo < hi) { int mid = (lo + hi) >> 1; if (batch[mid] < g) lo = mid + 1; else hi = mid; }
    int start = lo;
    hi = N_NODES;
    while (lo < hi) { int mid = (lo + hi) >> 1; if (batch[mid] < g + 1) lo = mid + 1; else hi = mid; }
    int end = lo;
    float a0 = 0.f, a1 = 0.f;
    for (int n = start + lane; n < end; n += 64) {
        float2 v = az[n];
        a0 += v.x; a1 += v.y;
    }
    for (int o = 32; o; o >>= 1) { a0 += __shfl_xor(a0, o); a1 += __shfl_xor(a1, o); }
    if (lane == 0) {
        if (end > start) {
            float inv = 1.0f / (float)(end - start);
            out[g * 2 + 0] = a0 * inv + w3buf[256];
            out[g * 2 + 1] = a1 * inv + w3buf[257];
        } else {
            out[g * 2 + 0] = w3buf[258];
            out[g * 2 + 1] = w3buf[259];
        }
    }
}

// ---------------- launch ----------------

extern "C" void kernel_launch(void* const* d_in, const int* in_sizes, int n_in,
                              void* d_out, int out_size, void* d_ws, size_t ws_size,
                              hipStream_t stream) {
    const float* x    = (const float*)d_in[0];
    const float* W1   = (const float*)d_in[1];
    const float* b1   = (const float*)d_in[2];
    const float* W2   = (const float*)d_in[3];
    const float* b2   = (const float*)d_in[4];
    const float* W3   = (const float*)d_in[5];
    const float* b3   = (const float*)d_in[6];
    const float* Wlin = (const float*)d_in[7];
    const float* blin = (const float*)d_in[8];
    const int*   eidx = (const int*)d_in[9];
    const int*   batch= (const int*)d_in[10];
    const int* esrc = eidx;
    const int* edst = eidx + N_EDGES;
    float* out = (float*)d_out;

    char* w = (char*)d_ws;
    size_t off = 0;
    auto alloc = [&](size_t bytes) { size_t o = off; off = (off + bytes + 255) & ~(size_t)255; return o; };
    int*   cnt    = (int*)  (w + alloc(N_NODES * 4));
    int*   rowptr = (int*)  (w + alloc((N_NODES + 1) * 4));
    int*   csr    = (int*)  (w + alloc(N_EDGES * 4));
    int*   pos    = (int*)  (w + alloc(N_EDGES * 4));
    float* dinv   = (float*)(w + alloc(N_NODES * 4));
    float* xd     = (float*)(w + alloc(N_NODES * 4));
    float2* s1d   = (float2*)(w + alloc((size_t)N_NODES * 8));
    float* w3buf  = (float*)(w + alloc(260 * 4));
    float* zd     = (float*)(w + alloc((size_t)N_NODES * 2 * 4));
    float2* az    = (float2*)(w + alloc((size_t)N_NODES * 8));

    const int FB = (N_EDGES + 255) / 256;       // 2344
    const int QB = (N_NODES * 4 + 255) / 256;   // 782 (4 lanes/node)
    // 1: zero cnt
    hipMemsetAsync(cnt, 0, N_NODES * 4, stream);
    // 2: degree count + pos + w3lin precompute (extra block)
    k_count<<<EB, 256, 0, stream>>>(edst, cnt, pos, W3, Wlin, b3, blin, w3buf);
    // 3: rowptr + dinv + xd (chunk prefix in-kernel)
    k_rowptr<<<NB_SCAN, 256, 0, stream>>>(cnt, x, rowptr, dinv, xd);
    // 4: CSR fill (atomic-free)
    k_fill<<<FB, 256, 0, stream>>>(esrc, edst, rowptr, pos, csr);
    // 5: layer-1 scalar aggregate (4 lanes/node)
    k_s1d<<<QB, 256, 0, stream>>>(x, xd, dinv, rowptr, csr, s1d);
    // 6: fused reconstruct + GEMM + relu + projection -> zd [N,2]
    k_gemm_fused<<<(N_NODES + 31) / 32, 256, 0, stream>>>(s1d, rowptr, csr,
                                                          W1, b1, W2, b2, w3buf, zd);
    // 7: layer-3 aggregation on zd (4 lanes/node) -> az, NO atomics
    k_aggz<<<QB, 256, 0, stream>>>(zd, rowptr, csr, dinv, az);
    // 8: per-graph segment mean + consts (one wave per graph)
    k_final<<<NG, 64, 0, stream>>>(az, batch, w3buf, out);
}

// Round 16
// 187.099 us; speedup vs baseline: 1.3571x; 1.1222x over previous
//
#include <hip/hip_runtime.h>
#include <hip/hip_bf16.h>

#define N_NODES 50000
#define N_EDGES 600000
#define HID     128
#define NG      500
#define NB_SCAN 196   // ceil(50000/256)
#define EB      2345  // ceil(600000/256) + 1 extra block for w3lin
#define MAXDEG  48    // ELL row slots; Poisson(12) max over 50k nodes ~30; +10 sigma safe
#define ELLS    49    // LDS stride (float2) for staged neighbor values; 48 -> 32-way bank conflict

// ---------------- single-pass ELL fill (+ last block computes w3lin = W3@Wlin) ----------------

__global__ void k_ellfill(const int* __restrict__ src, const int* __restrict__ dst,
                          int* __restrict__ cnt, int* __restrict__ ell,
                          const float* __restrict__ W3, const float* __restrict__ Wlin,
                          const float* __restrict__ b3, const float* __restrict__ blin,
                          float* __restrict__ w3buf) {
    if (blockIdx.x == EB - 1) {
        int t = threadIdx.x;          // 256 threads -> 128x2
        int k = t >> 1, j = t & 1;
        float acc = 0.f;
        for (int m = 0; m < 128; m++) acc += W3[k * 128 + m] * Wlin[m * 2 + j];
        w3buf[k * 2 + j] = acc;
        if (t < 2) {
            float c = 0.f;
            for (int m = 0; m < 128; m++) c += b3[m] * Wlin[m * 2 + t];
            w3buf[256 + t] = c + blin[t];   // const added to every non-empty graph
            w3buf[258 + t] = blin[t];       // empty-graph fallback
        }
        return;
    }
    int e = blockIdx.x * 256 + threadIdx.x;
    if (e < N_EDGES) {
        int d = dst[e];
        int p = atomicAdd(&cnt[d], 1);
        if (p < MAXDEG) ell[d * MAXDEG + p] = src[e];
    }
}

// dinv + xd (coalesced; NO scan — ELL rows are directly addressable)
__global__ void k_nodeprep(const int* __restrict__ cnt, const float* __restrict__ x,
                           float* __restrict__ dinv, float* __restrict__ xd) {
    int i = blockIdx.x * 256 + threadIdx.x;
    if (i < N_NODES) {
        float di = rsqrtf((float)cnt[i] + 1.0f);
        dinv[i] = di;
        xd[i] = x[i] * di;
    }
}

// layer-1 scalar aggregate, 4 lanes/node over ELL row: s1d[i] = {x_i*di^2 + (Σ xd[j])*di, di}
__global__ void k_s1d(const float* __restrict__ x, const float* __restrict__ xd,
                      const float* __restrict__ dinv, const int* __restrict__ cnt,
                      const int* __restrict__ ell, float2* __restrict__ s1d) {
    int tid = blockIdx.x * 256 + threadIdx.x;
    int i = tid >> 2, sub = tid & 3;
    if (i >= N_NODES) return;
    int c = min(cnt[i], MAXDEG);
    const int* row = &ell[i * MAXDEG];
    float acc = 0.f;
    for (int p = sub; p < c; p += 4) acc += xd[row[p]];
    acc += __shfl_xor(acc, 1);
    acc += __shfl_xor(acc, 2);
    if (sub == 0) {
        float di = dinv[i];
        float2 r = {x[i] * di * di + acc * di, di};
        s1d[i] = r;
    }
}

// ---------------- Fused: reconstruct-aggregate g=A·h1, GEMM g@W2, relu+b2, ·w3lin -> zd[N,2]
// 32-row tile (R12-proven shape). Neighbor s1d values staged once into padded LDS
// (stride ELLS=49 float2 -> 2-way bank access, free). GEMM: W2 from global (L2-resident).
// Epilogue stores zd = z*dinv so layer-3 needs a single gather per edge.

__global__ __launch_bounds__(256) void k_gemm_fused(const float2* __restrict__ s1d,
                                                    const int* __restrict__ cnt,
                                                    const int* __restrict__ ell,
                                                    const float* __restrict__ W1,
                                                    const float* __restrict__ b1,
                                                    const float* __restrict__ W2,
                                                    const float* __restrict__ b2,
                                                    const float* __restrict__ w3buf,
                                                    float* __restrict__ zd) {
    __shared__ float HsT[128 * 32];       // 16 KB, [ch][r]
    __shared__ float2 sjd_sh[32 * ELLS];  // 12.25 KB, [r][p] padded
    __shared__ int cnt_sh[32];
    int t = threadIdx.x;
    int r0 = blockIdx.x * 32;
    int lane = t & 31, grp = t >> 5;  // lane = row in tile, grp = 16-channel chunk (8 x 16)

    if (t < 32) {
        int i = r0 + t;
        cnt_sh[t] = (i < N_NODES) ? min(cnt[i], MAXDEG) : 0;
    }
    __syncthreads();
    // stage neighbor s1d values: slot-parallel over 32 x MAXDEG padded rows
    for (int slot = t; slot < 32 * MAXDEG; slot += 256) {
        int r = slot / MAXDEG, p = slot - r * MAXDEG;
        if (p < cnt_sh[r]) {
            int j = ell[(r0 + r) * MAXDEG + p];
            sjd_sh[r * ELLS + p] = s1d[j];
        }
    }
    __syncthreads();

    float w1r[16], b1r[16];
    #pragma unroll
    for (int kk = 0; kk < 16; kk++) { w1r[kk] = W1[grp * 16 + kk]; b1r[kk] = b1[grp * 16 + kk]; }

    float ga[16];
    #pragma unroll
    for (int kk = 0; kk < 16; kk++) ga[kk] = 0.f;
    int node = r0 + lane;
    if (node < N_NODES) {
        float2 sd = s1d[node];
        float di = sd.y, wself = sd.y * sd.y;
        #pragma unroll
        for (int kk = 0; kk < 16; kk++) ga[kk] = fmaxf(sd.x * w1r[kk] + b1r[kk], 0.f) * wself;
        int c = cnt_sh[lane];
        const float2* myrow = &sjd_sh[lane * ELLS];
        int p = 0;
        for (; p + 3 < c; p += 4) {
            float2 s0 = myrow[p], s1v = myrow[p+1], s2 = myrow[p+2], s3 = myrow[p+3];
            float wj0 = s0.y * di, wj1 = s1v.y * di, wj2 = s2.y * di, wj3 = s3.y * di;
            #pragma unroll
            for (int kk = 0; kk < 16; kk++) {
                ga[kk] += fmaxf(s0.x  * w1r[kk] + b1r[kk], 0.f) * wj0
                        + fmaxf(s1v.x * w1r[kk] + b1r[kk], 0.f) * wj1
                        + fmaxf(s2.x  * w1r[kk] + b1r[kk], 0.f) * wj2
                        + fmaxf(s3.x  * w1r[kk] + b1r[kk], 0.f) * wj3;
            }
        }
        for (; p < c; p++) {
            float2 sj = myrow[p];
            float wj = sj.y * di;
            #pragma unroll
            for (int kk = 0; kk < 16; kk++)
                ga[kk] += fmaxf(sj.x * w1r[kk] + b1r[kk], 0.f) * wj;
        }
    }
    #pragma unroll
    for (int kk = 0; kk < 16; kk++) HsT[(grp * 16 + kk) * 32 + lane] = ga[kk];
    __syncthreads();

    // GEMM: 32 rows x 128 cols; each thread 4 rows x 4 cols
    int col = (t & 31) * 4;       // 0..124
    int row = (t >> 5) * 4;       // 0..28
    float a[4][4] = {};
    #pragma unroll 4
    for (int k = 0; k < 128; k++) {
        float4 w = *(const float4*)&W2[k * 128 + col];
        float4 h = *(float4*)&HsT[k * 32 + row];
        a[0][0] += h.x * w.x; a[0][1] += h.x * w.y; a[0][2] += h.x * w.z; a[0][3] += h.x * w.w;
        a[1][0] += h.y * w.x; a[1][1] += h.y * w.y; a[1][2] += h.y * w.z; a[1][3] += h.y * w.w;
        a[2][0] += h.z * w.x; a[2][1] += h.z * w.y; a[2][2] += h.z * w.z; a[2][3] += h.z * w.w;
        a[3][0] += h.w * w.x; a[3][1] += h.w * w.y; a[3][2] += h.w * w.z; a[3][3] += h.w * w.w;
    }

    // epilogue: relu(+b2), project to 2 outputs, reduce across 32 lanes, scale by dinv
    float b2r[4], w0r[4], w1rr[4];
    #pragma unroll
    for (int c = 0; c < 4; c++) {
        b2r[c] = b2[col + c];
        w0r[c] = w3buf[(col + c) * 2 + 0];
        w1rr[c] = w3buf[(col + c) * 2 + 1];
    }
    #pragma unroll
    for (int r = 0; r < 4; r++) {
        float p0 = 0.f, p1 = 0.f;
        #pragma unroll
        for (int c = 0; c < 4; c++) {
            float v0 = fmaxf(a[r][c] + b2r[c], 0.f);
            p0 += v0 * w0r[c];
            p1 += v0 * w1rr[c];
        }
        for (int o = 1; o < 32; o <<= 1) { p0 += __shfl_xor(p0, o); p1 += __shfl_xor(p1, o); }
        int rg = r0 + row + r;
        if ((t & 31) == 0 && rg < N_NODES) {
            float dr = s1d[rg].y;
            zd[rg * 2 + 0] = p0 * dr;
            zd[rg * 2 + 1] = p1 * dr;
        }
    }
}

// ---------------- Layer-3 aggregation on zd, 4 lanes/node over ELL row -> plain az store ----

__global__ void k_aggz(const float* __restrict__ zd, const int* __restrict__ cnt,
                       const int* __restrict__ ell, const float* __restrict__ dinv,
                       float2* __restrict__ az) {
    int tid = blockIdx.x * 256 + threadIdx.x;
    int i = tid >> 2, sub = tid & 3;
    if (i >= N_NODES) return;
    const float2* Z = (const float2*)zd;
    int c = min(cnt[i], MAXDEG);
    const int* row = &ell[i * MAXDEG];
    float a0 = 0.f, a1 = 0.f;
    for (int p = sub; p < c; p += 4) {
        float2 zj = Z[row[p]];
        a0 += zj.x; a1 += zj.y;
    }
    a0 += __shfl_xor(a0, 1); a1 += __shfl_xor(a1, 1);
    a0 += __shfl_xor(a0, 2); a1 += __shfl_xor(a1, 2);
    if (sub == 0) {
        float di = dinv[i];
        float2 zi = Z[i];
        float2 r = {(zi.x + a0) * di, (zi.y + a1) * di};   // zd_i*di + di*Σ zd_j
        az[i] = r;
    }
}

// ---------------- Final: one wave per graph — segment sum of az + mean + consts ----------------

__global__ __launch_bounds__(64) void k_final(const float2* __restrict__ az,
                                              const int* __restrict__ batch,
                                              const float* __restrict__ w3buf,
                                              float* __restrict__ out) {
    int g = blockIdx.x;
    int lane = threadIdx.x;
    int lo = 0, hi = N_NODES;
    while (lo < hi) { int mid = (lo + hi) >> 1; if (batch[mid] < g) lo = mid + 1; else hi = mid; }
    int start = lo;
    hi = N_NODES;
    while (lo < hi) { int mid = (lo + hi) >> 1; if (batch[mid] < g + 1) lo = mid + 1; else hi = mid; }
    int end = lo;
    float a0 = 0.f, a1 = 0.f;
    for (int n = start + lane; n < end; n += 64) {
        float2 v = az[n];
        a0 += v.x; a1 += v.y;
    }
    for (int o = 32; o; o >>= 1) { a0 += __shfl_xor(a0, o); a1 += __shfl_xor(a1, o); }
    if (lane == 0) {
        if (end > start) {
            float inv = 1.0f / (float)(end - start);
            out[g * 2 + 0] = a0 * inv + w3buf[256];
            out[g * 2 + 1] = a1 * inv + w3buf[257];
        } else {
            out[g * 2 + 0] = w3buf[258];
            out[g * 2 + 1] = w3buf[259];
        }
    }
}

// ---------------- launch ----------------

extern "C" void kernel_launch(void* const* d_in, const int* in_sizes, int n_in,
                              void* d_out, int out_size, void* d_ws, size_t ws_size,
                              hipStream_t stream) {
    const float* x    = (const float*)d_in[0];
    const float* W1   = (const float*)d_in[1];
    const float* b1   = (const float*)d_in[2];
    const float* W2   = (const float*)d_in[3];
    const float* b2   = (const float*)d_in[4];
    const float* W3   = (const float*)d_in[5];
    const float* b3   = (const float*)d_in[6];
    const float* Wlin = (const float*)d_in[7];
    const float* blin = (const float*)d_in[8];
    const int*   eidx = (const int*)d_in[9];
    const int*   batch= (const int*)d_in[10];
    const int* esrc = eidx;
    const int* edst = eidx + N_EDGES;
    float* out = (float*)d_out;

    char* w = (char*)d_ws;
    size_t off = 0;
    auto alloc = [&](size_t bytes) { size_t o = off; off = (off + bytes + 255) & ~(size_t)255; return o; };
    int*   cnt    = (int*)  (w + alloc(N_NODES * 4));
    int*   ell    = (int*)  (w + alloc((size_t)N_NODES * MAXDEG * 4));   // 9.6 MB
    float* dinv   = (float*)(w + alloc(N_NODES * 4));
    float* xd     = (float*)(w + alloc(N_NODES * 4));
    float2* s1d   = (float2*)(w + alloc((size_t)N_NODES * 8));
    float* w3buf  = (float*)(w + alloc(260 * 4));
    float* zd     = (float*)(w + alloc((size_t)N_NODES * 2 * 4));
    float2* az    = (float2*)(w + alloc((size_t)N_NODES * 8));

    const int QB = (N_NODES * 4 + 255) / 256;   // 782 (4 lanes/node)
    // 1: zero cnt
    hipMemsetAsync(cnt, 0, N_NODES * 4, stream);
    // 2: single-pass ELL build + w3lin precompute (extra block)
    k_ellfill<<<EB, 256, 0, stream>>>(esrc, edst, cnt, ell, W3, Wlin, b3, blin, w3buf);
    // 3: dinv + xd (no scan)
    k_nodeprep<<<NB_SCAN, 256, 0, stream>>>(cnt, x, dinv, xd);
    // 4: layer-1 scalar aggregate (4 lanes/node, ELL rows)
    k_s1d<<<QB, 256, 0, stream>>>(x, xd, dinv, cnt, ell, s1d);
    // 5: fused reconstruct + GEMM + relu + projection -> zd [N,2]
    k_gemm_fused<<<(N_NODES + 31) / 32, 256, 0, stream>>>(s1d, cnt, ell,
                                                          W1, b1, W2, b2, w3buf, zd);
    // 6: layer-3 aggregation on zd (4 lanes/node, ELL rows) -> az
    k_aggz<<<QB, 256, 0, stream>>>(zd, cnt, ell, dinv, az);
    // 7: per-graph segment mean + consts (one wave per graph)
    k_final<<<NG, 64, 0, stream>>>(az, batch, w3buf, out);
}

// Round 17
// 182.308 us; speedup vs baseline: 1.3928x; 1.0263x over previous
//
#include <hip/hip_runtime.h>
#include <hip/hip_bf16.h>

#define N_NODES 50000
#define N_EDGES 600000
#define HID     128
#define NG      500
#define NB_SCAN 196   // ceil(50000/256)
#define EB      2345  // ceil(600000/256) + 1 extra block for w3lin
#define MAXDEG  48    // ELL row slots; Poisson(12) max over 50k nodes ~30; +10 sigma safe
#define ECAP    768   // compact LDS staging capacity (32 rows x mean 12 = 384; +6 sigma)

// ---------------- single-pass ELL fill (+ last block computes w3lin = W3@Wlin) ----------------

__global__ void k_ellfill(const int* __restrict__ src, const int* __restrict__ dst,
                          int* __restrict__ cnt, int* __restrict__ ell,
                          const float* __restrict__ W3, const float* __restrict__ Wlin,
                          const float* __restrict__ b3, const float* __restrict__ blin,
                          float* __restrict__ w3buf) {
    if (blockIdx.x == EB - 1) {
        int t = threadIdx.x;          // 256 threads -> 128x2
        int k = t >> 1, j = t & 1;
        float acc = 0.f;
        for (int m = 0; m < 128; m++) acc += W3[k * 128 + m] * Wlin[m * 2 + j];
        w3buf[k * 2 + j] = acc;
        if (t < 2) {
            float c = 0.f;
            for (int m = 0; m < 128; m++) c += b3[m] * Wlin[m * 2 + t];
            w3buf[256 + t] = c + blin[t];   // const added to every non-empty graph
            w3buf[258 + t] = blin[t];       // empty-graph fallback
        }
        return;
    }
    int e = blockIdx.x * 256 + threadIdx.x;
    if (e < N_EDGES) {
        int d = dst[e];
        int p = atomicAdd(&cnt[d], 1);
        if (p < MAXDEG) ell[d * MAXDEG + p] = src[e];
    }
}

// dinv + xd (coalesced; NO scan — ELL rows are directly addressable)
__global__ void k_nodeprep(const int* __restrict__ cnt, const float* __restrict__ x,
                           float* __restrict__ dinv, float* __restrict__ xd) {
    int i = blockIdx.x * 256 + threadIdx.x;
    if (i < N_NODES) {
        float di = rsqrtf((float)cnt[i] + 1.0f);
        dinv[i] = di;
        xd[i] = x[i] * di;
    }
}

// layer-1 scalar aggregate, 4 lanes/node over ELL row: s1d[i] = {x_i*di^2 + (Σ xd[j])*di, di}
__global__ void k_s1d(const float* __restrict__ x, const float* __restrict__ xd,
                      const float* __restrict__ dinv, const int* __restrict__ cnt,
                      const int* __restrict__ ell, float2* __restrict__ s1d) {
    int tid = blockIdx.x * 256 + threadIdx.x;
    int i = tid >> 2, sub = tid & 3;
    if (i >= N_NODES) return;
    int c = min(cnt[i], MAXDEG);
    const int* row = &ell[i * MAXDEG];
    float acc = 0.f;
    for (int p = sub; p < c; p += 4) acc += xd[row[p]];
    acc += __shfl_xor(acc, 1);
    acc += __shfl_xor(acc, 2);
    if (sub == 0) {
        float di = dinv[i];
        float2 r = {x[i] * di * di + acc * di, di};
        s1d[i] = r;
    }
}

// ---------------- Fused: reconstruct-aggregate g=A·h1, GEMM g@W2, relu+b2, ·w3lin -> zd[N,2]
// 32-row tile. Neighbor s1d staged COMPACTED into LDS (block prefix over cnt_sh; 6KB not
// 12.25KB padded — R16 lesson: LDS size → occupancy → throughput). W2 from global (L2).

__global__ __launch_bounds__(256) void k_gemm_fused(const float2* __restrict__ s1d,
                                                    const int* __restrict__ cnt,
                                                    const int* __restrict__ ell,
                                                    const float* __restrict__ W1,
                                                    const float* __restrict__ b1,
                                                    const float* __restrict__ W2,
                                                    const float* __restrict__ b2,
                                                    const float* __restrict__ w3buf,
                                                    float* __restrict__ zd) {
    __shared__ float HsT[128 * 32];       // 16 KB, [ch][r]
    __shared__ float2 sjd_sh[ECAP];       // 6 KB, compacted
    __shared__ int cnt_sh[32];
    __shared__ int pref_sh[33];           // exclusive prefix; pref_sh[32] = total
    int t = threadIdx.x;
    int r0 = blockIdx.x * 32;
    int lane = t & 31, grp = t >> 5;  // lane = row in tile, grp = 16-channel chunk (8 x 16)

    if (t < 32) {
        int i = r0 + t;
        int c = (i < N_NODES) ? min(cnt[i], MAXDEG) : 0;
        cnt_sh[t] = c;
        // inclusive shuffle scan over the first 32 lanes of wave 0
        int inc = c;
        for (int o = 1; o < 32; o <<= 1) {
            int u = __shfl_up(inc, o);
            if (t >= o) inc += u;
        }
        pref_sh[t] = inc - c;
        if (t == 31) pref_sh[32] = inc;
    }
    __syncthreads();
    int total = pref_sh[32];
    bool fast = (total <= ECAP);
    if (fast) {
        // compacted staging: slot-parallel over padded slots, write to pref[r]+p
        for (int slot = t; slot < 32 * MAXDEG; slot += 256) {
            int r = slot / MAXDEG, p = slot - r * MAXDEG;
            if (p < cnt_sh[r]) {
                int j = ell[(r0 + r) * MAXDEG + p];
                sjd_sh[pref_sh[r] + p] = s1d[j];
            }
        }
    }
    __syncthreads();

    float w1r[16], b1r[16];
    #pragma unroll
    for (int kk = 0; kk < 16; kk++) { w1r[kk] = W1[grp * 16 + kk]; b1r[kk] = b1[grp * 16 + kk]; }

    float ga[16];
    #pragma unroll
    for (int kk = 0; kk < 16; kk++) ga[kk] = 0.f;
    int node = r0 + lane;
    if (node < N_NODES) {
        float2 sd = s1d[node];
        float di = sd.y, wself = sd.y * sd.y;
        #pragma unroll
        for (int kk = 0; kk < 16; kk++) ga[kk] = fmaxf(sd.x * w1r[kk] + b1r[kk], 0.f) * wself;
        int c = cnt_sh[lane];
        if (fast) {
            const float2* myrow = &sjd_sh[pref_sh[lane]];
            int p = 0;
            for (; p + 3 < c; p += 4) {
                float2 s0 = myrow[p], s1v = myrow[p+1], s2 = myrow[p+2], s3 = myrow[p+3];
                float wj0 = s0.y * di, wj1 = s1v.y * di, wj2 = s2.y * di, wj3 = s3.y * di;
                #pragma unroll
                for (int kk = 0; kk < 16; kk++) {
                    ga[kk] += fmaxf(s0.x  * w1r[kk] + b1r[kk], 0.f) * wj0
                            + fmaxf(s1v.x * w1r[kk] + b1r[kk], 0.f) * wj1
                            + fmaxf(s2.x  * w1r[kk] + b1r[kk], 0.f) * wj2
                            + fmaxf(s3.x  * w1r[kk] + b1r[kk], 0.f) * wj3;
                }
            }
            for (; p < c; p++) {
                float2 sj = myrow[p];
                float wj = sj.y * di;
                #pragma unroll
                for (int kk = 0; kk < 16; kk++)
                    ga[kk] += fmaxf(sj.x * w1r[kk] + b1r[kk], 0.f) * wj;
            }
        } else {   // overflow fallback (block-uniform, ~never taken)
            const int* row = &ell[(size_t)node * MAXDEG];
            for (int p = 0; p < c; p++) {
                float2 sj = s1d[row[p]];
                float wj = sj.y * di;
                #pragma unroll
                for (int kk = 0; kk < 16; kk++)
                    ga[kk] += fmaxf(sj.x * w1r[kk] + b1r[kk], 0.f) * wj;
            }
        }
    }
    #pragma unroll
    for (int kk = 0; kk < 16; kk++) HsT[(grp * 16 + kk) * 32 + lane] = ga[kk];
    __syncthreads();

    // GEMM: 32 rows x 128 cols; each thread 4 rows x 4 cols
    int col = (t & 31) * 4;       // 0..124
    int row = (t >> 5) * 4;       // 0..28
    float a[4][4] = {};
    #pragma unroll 4
    for (int k = 0; k < 128; k++) {
        float4 w = *(const float4*)&W2[k * 128 + col];
        float4 h = *(float4*)&HsT[k * 32 + row];
        a[0][0] += h.x * w.x; a[0][1] += h.x * w.y; a[0][2] += h.x * w.z; a[0][3] += h.x * w.w;
        a[1][0] += h.y * w.x; a[1][1] += h.y * w.y; a[1][2] += h.y * w.z; a[1][3] += h.y * w.w;
        a[2][0] += h.z * w.x; a[2][1] += h.z * w.y; a[2][2] += h.z * w.z; a[2][3] += h.z * w.w;
        a[3][0] += h.w * w.x; a[3][1] += h.w * w.y; a[3][2] += h.w * w.z; a[3][3] += h.w * w.w;
    }

    // epilogue: relu(+b2), project to 2 outputs, reduce across 32 lanes, scale by dinv
    float b2r[4], w0r[4], w1rr[4];
    #pragma unroll
    for (int c = 0; c < 4; c++) {
        b2r[c] = b2[col + c];
        w0r[c] = w3buf[(col + c) * 2 + 0];
        w1rr[c] = w3buf[(col + c) * 2 + 1];
    }
    #pragma unroll
    for (int r = 0; r < 4; r++) {
        float p0 = 0.f, p1 = 0.f;
        #pragma unroll
        for (int c = 0; c < 4; c++) {
            float v0 = fmaxf(a[r][c] + b2r[c], 0.f);
            p0 += v0 * w0r[c];
            p1 += v0 * w1rr[c];
        }
        for (int o = 1; o < 32; o <<= 1) { p0 += __shfl_xor(p0, o); p1 += __shfl_xor(p1, o); }
        int rg = r0 + row + r;
        if ((t & 31) == 0 && rg < N_NODES) {
            float dr = s1d[rg].y;
            zd[rg * 2 + 0] = p0 * dr;
            zd[rg * 2 + 1] = p1 * dr;
        }
    }
}

// ---------------- Layer-3 aggregation on zd, 4 lanes/node over ELL row -> plain az store ----

__global__ void k_aggz(const float* __restrict__ zd, const int* __restrict__ cnt,
                       const int* __restrict__ ell, const float* __restrict__ dinv,
                       float2* __restrict__ az) {
    int tid = blockIdx.x * 256 + threadIdx.x;
    int i = tid >> 2, sub = tid & 3;
    if (i >= N_NODES) return;
    const float2* Z = (const float2*)zd;
    int c = min(cnt[i], MAXDEG);
    const int* row = &ell[i * MAXDEG];
    float a0 = 0.f, a1 = 0.f;
    for (int p = sub; p < c; p += 4) {
        float2 zj = Z[row[p]];
        a0 += zj.x; a1 += zj.y;
    }
    a0 += __shfl_xor(a0, 1); a1 += __shfl_xor(a1, 1);
    a0 += __shfl_xor(a0, 2); a1 += __shfl_xor(a1, 2);
    if (sub == 0) {
        float di = dinv[i];
        float2 zi = Z[i];
        float2 r = {(zi.x + a0) * di, (zi.y + a1) * di};   // zd_i*di + di*Σ zd_j
        az[i] = r;
    }
}

// ---------------- Final: one wave per graph — segment sum of az + mean + consts ----------------

__global__ __launch_bounds__(64) void k_final(const float2* __restrict__ az,
                                              const int* __restrict__ batch,
                                              const float* __restrict__ w3buf,
                                              float* __restrict__ out) {
    int g = blockIdx.x;
    int lane = threadIdx.x;
    int lo = 0, hi = N_NODES;
    while (lo < hi) { int mid = (lo + hi) >> 1; if (batch[mid] < g) lo = mid + 1; else hi = mid; }
    int start = lo;
    hi = N_NODES;
    while (lo < hi) { int mid = (lo + hi) >> 1; if (batch[mid] < g + 1) lo = mid + 1; else hi = mid; }
    int end = lo;
    float a0 = 0.f, a1 = 0.f;
    for (int n = start + lane; n < end; n += 64) {
        float2 v = az[n];
        a0 += v.x; a1 += v.y;
    }
    for (int o = 32; o; o >>= 1) { a0 += __shfl_xor(a0, o); a1 += __shfl_xor(a1, o); }
    if (lane == 0) {
        if (end > start) {
            float inv = 1.0f / (float)(end - start);
            out[g * 2 + 0] = a0 * inv + w3buf[256];
            out[g * 2 + 1] = a1 * inv + w3buf[257];
        } else {
            out[g * 2 + 0] = w3buf[258];
            out[g * 2 + 1] = w3buf[259];
        }
    }
}

// ---------------- launch ----------------

extern "C" void kernel_launch(void* const* d_in, const int* in_sizes, int n_in,
                              void* d_out, int out_size, void* d_ws, size_t ws_size,
                              hipStream_t stream) {
    const float* x    = (const float*)d_in[0];
    const float* W1   = (const float*)d_in[1];
    const float* b1   = (const float*)d_in[2];
    const float* W2   = (const float*)d_in[3];
    const float* b2   = (const float*)d_in[4];
    const float* W3   = (const float*)d_in[5];
    const float* b3   = (const float*)d_in[6];
    const float* Wlin = (const float*)d_in[7];
    const float* blin = (const float*)d_in[8];
    const int*   eidx = (const int*)d_in[9];
    const int*   batch= (const int*)d_in[10];
    const int* esrc = eidx;
    const int* edst = eidx + N_EDGES;
    float* out = (float*)d_out;

    char* w = (char*)d_ws;
    size_t off = 0;
    auto alloc = [&](size_t bytes) { size_t o = off; off = (off + bytes + 255) & ~(size_t)255; return o; };
    int*   cnt    = (int*)  (w + alloc(N_NODES * 4));
    int*   ell    = (int*)  (w + alloc((size_t)N_NODES * MAXDEG * 4));   // 9.6 MB
    float* dinv   = (float*)(w + alloc(N_NODES * 4));
    float* xd     = (float*)(w + alloc(N_NODES * 4));
    float2* s1d   = (float2*)(w + alloc((size_t)N_NODES * 8));
    float* w3buf  = (float*)(w + alloc(260 * 4));
    float* zd     = (float*)(w + alloc((size_t)N_NODES * 2 * 4));
    float2* az    = (float2*)(w + alloc((size_t)N_NODES * 8));

    const int QB = (N_NODES * 4 + 255) / 256;   // 782 (4 lanes/node)
    // 1: zero cnt
    hipMemsetAsync(cnt, 0, N_NODES * 4, stream);
    // 2: single-pass ELL build + w3lin precompute (extra block)
    k_ellfill<<<EB, 256, 0, stream>>>(esrc, edst, cnt, ell, W3, Wlin, b3, blin, w3buf);
    // 3: dinv + xd (no scan)
    k_nodeprep<<<NB_SCAN, 256, 0, stream>>>(cnt, x, dinv, xd);
    // 4: layer-1 scalar aggregate (4 lanes/node, ELL rows)
    k_s1d<<<QB, 256, 0, stream>>>(x, xd, dinv, cnt, ell, s1d);
    // 5: fused reconstruct + GEMM + relu + projection -> zd [N,2]  (compact LDS staging)
    k_gemm_fused<<<(N_NODES + 31) / 32, 256, 0, stream>>>(s1d, cnt, ell,
                                                          W1, b1, W2, b2, w3buf, zd);
    // 6: layer-3 aggregation on zd (4 lanes/node, ELL rows) -> az
    k_aggz<<<QB, 256, 0, stream>>>(zd, cnt, ell, dinv, az);
    // 7: per-graph segment mean + consts (one wave per graph)
    k_final<<<NG, 64, 0, stream>>>(az, batch, w3buf, out);
}

// Round 18
// 181.331 us; speedup vs baseline: 1.4003x; 1.0054x over previous
//
#include <hip/hip_runtime.h>
#include <hip/hip_bf16.h>

#define N_NODES 50000
#define N_EDGES 600000
#define HID     128
#define NG      500
#define NB_SCAN 196   // ceil(50000/256)
#define MAXDEG  48    // ELL slots; Poisson(12) max over 50k nodes ~30; +10 sigma safe
#define ECAP    768   // compact LDS staging capacity (32 rows x mean 12 = 384; +6 sigma)
#define EB2     1174  // ceil(600000/512) + 1 extra block for w3lin

// ---------------- single-pass transposed-ELL fill, 2 edges/thread (+ w3lin block) ------------

__global__ void k_ellfill(const int* __restrict__ src, const int* __restrict__ dst,
                          int* __restrict__ cnt, int* __restrict__ ell_t,
                          const float* __restrict__ W3, const float* __restrict__ Wlin,
                          const float* __restrict__ b3, const float* __restrict__ blin,
                          float* __restrict__ w3buf) {
    if (blockIdx.x == EB2 - 1) {
        int t = threadIdx.x;          // 256 threads -> 128x2
        int k = t >> 1, j = t & 1;
        float acc = 0.f;
        for (int m = 0; m < 128; m++) acc += W3[k * 128 + m] * Wlin[m * 2 + j];
        w3buf[k * 2 + j] = acc;
        if (t < 2) {
            float c = 0.f;
            for (int m = 0; m < 128; m++) c += b3[m] * Wlin[m * 2 + t];
            w3buf[256 + t] = c + blin[t];   // const added to every non-empty graph
            w3buf[258 + t] = blin[t];       // empty-graph fallback
        }
        return;
    }
    int e0 = blockIdx.x * 512 + threadIdx.x;
    int e1 = e0 + 256;
    // two independent atomic->store chains, both in flight
    if (e0 < N_EDGES) {
        int d0 = dst[e0];
        int p0 = atomicAdd(&cnt[d0], 1);
        if (p0 < MAXDEG) ell_t[p0 * N_NODES + d0] = src[e0];
    }
    if (e1 < N_EDGES) {
        int d1 = dst[e1];
        int p1 = atomicAdd(&cnt[d1], 1);
        if (p1 < MAXDEG) ell_t[p1 * N_NODES + d1] = src[e1];
    }
}

// dinv + xd (coalesced)
__global__ void k_nodeprep(const int* __restrict__ cnt, const float* __restrict__ x,
                           float* __restrict__ dinv, float* __restrict__ xd) {
    int i = blockIdx.x * 256 + threadIdx.x;
    if (i < N_NODES) {
        float di = rsqrtf((float)cnt[i] + 1.0f);
        dinv[i] = di;
        xd[i] = x[i] * di;
    }
}

// layer-1 scalar aggregate, 4 lanes/node, plane-strided transposed reads (4 lines/wave):
// s1d[i] = {x_i*di^2 + (Σ xd[j])*di, di}
__global__ void k_s1d(const float* __restrict__ x, const float* __restrict__ xd,
                      const float* __restrict__ dinv, const int* __restrict__ cnt,
                      const int* __restrict__ ell_t, float2* __restrict__ s1d) {
    int tid = blockIdx.x * 256 + threadIdx.x;
    int i = tid >> 2, sub = tid & 3;
    if (i >= N_NODES) return;
    int c = min(cnt[i], MAXDEG);
    float acc = 0.f;
    for (int p = sub; p < c; p += 4) acc += xd[ell_t[p * N_NODES + i]];
    acc += __shfl_xor(acc, 1);
    acc += __shfl_xor(acc, 2);
    if (sub == 0) {
        float di = dinv[i];
        float2 r = {x[i] * di * di + acc * di, di};
        s1d[i] = r;
    }
}

// ---------------- Fused: reconstruct-aggregate g=A·h1, GEMM g@W2, relu+b2, ·w3lin -> zd[N,2]
// 32-row tile; compact LDS staging (6KB). Transposed-ELL staging: one plane for 32 rows per
// 32-lane chunk = coalesced 128B reads (R17 lesson: row-major ELL reads were sparse).

__global__ __launch_bounds__(256) void k_gemm_fused(const float2* __restrict__ s1d,
                                                    const int* __restrict__ cnt,
                                                    const int* __restrict__ ell_t,
                                                    const float* __restrict__ W1,
                                                    const float* __restrict__ b1,
                                                    const float* __restrict__ W2,
                                                    const float* __restrict__ b2,
                                                    const float* __restrict__ w3buf,
                                                    float* __restrict__ zd) {
    __shared__ float HsT[128 * 32];       // 16 KB, [ch][r]
    __shared__ float2 sjd_sh[ECAP];       // 6 KB, compacted
    __shared__ int cnt_sh[32];
    __shared__ int pref_sh[33];           // exclusive prefix; pref_sh[32] = total
    int t = threadIdx.x;
    int r0 = blockIdx.x * 32;
    int lane = t & 31, grp = t >> 5;  // lane = row in tile, grp = 16-channel chunk (8 x 16)

    if (t < 32) {
        int i = r0 + t;
        int c = (i < N_NODES) ? min(cnt[i], MAXDEG) : 0;
        cnt_sh[t] = c;
        int inc = c;
        for (int o = 1; o < 32; o <<= 1) {
            int u = __shfl_up(inc, o);
            if (t >= o) inc += u;
        }
        pref_sh[t] = inc - c;
        if (t == 31) pref_sh[32] = inc;
    }
    __syncthreads();
    int total = pref_sh[32];
    bool fast = (total <= ECAP);
    if (fast) {
        // staging: slot = (plane p, row ln); each 32-slot chunk reads one coalesced plane
        for (int slot = t; slot < 32 * MAXDEG; slot += 256) {
            int p = slot >> 5, ln = slot & 31;
            if (p < cnt_sh[ln]) {
                int j = ell_t[p * N_NODES + r0 + ln];
                sjd_sh[pref_sh[ln] + p] = s1d[j];
            }
        }
    }
    __syncthreads();

    float w1r[16], b1r[16];
    #pragma unroll
    for (int kk = 0; kk < 16; kk++) { w1r[kk] = W1[grp * 16 + kk]; b1r[kk] = b1[grp * 16 + kk]; }

    float ga[16];
    #pragma unroll
    for (int kk = 0; kk < 16; kk++) ga[kk] = 0.f;
    int node = r0 + lane;
    if (node < N_NODES) {
        float2 sd = s1d[node];
        float di = sd.y, wself = sd.y * sd.y;
        #pragma unroll
        for (int kk = 0; kk < 16; kk++) ga[kk] = fmaxf(sd.x * w1r[kk] + b1r[kk], 0.f) * wself;
        int c = cnt_sh[lane];
        if (fast) {
            const float2* myrow = &sjd_sh[pref_sh[lane]];
            int p = 0;
            for (; p + 3 < c; p += 4) {
                float2 s0 = myrow[p], s1v = myrow[p+1], s2 = myrow[p+2], s3 = myrow[p+3];
                float wj0 = s0.y * di, wj1 = s1v.y * di, wj2 = s2.y * di, wj3 = s3.y * di;
                #pragma unroll
                for (int kk = 0; kk < 16; kk++) {
                    ga[kk] += fmaxf(s0.x  * w1r[kk] + b1r[kk], 0.f) * wj0
                            + fmaxf(s1v.x * w1r[kk] + b1r[kk], 0.f) * wj1
                            + fmaxf(s2.x  * w1r[kk] + b1r[kk], 0.f) * wj2
                            + fmaxf(s3.x  * w1r[kk] + b1r[kk], 0.f) * wj3;
                }
            }
            for (; p < c; p++) {
                float2 sj = myrow[p];
                float wj = sj.y * di;
                #pragma unroll
                for (int kk = 0; kk < 16; kk++)
                    ga[kk] += fmaxf(sj.x * w1r[kk] + b1r[kk], 0.f) * wj;
            }
        } else {   // overflow fallback (block-uniform, ~never taken)
            for (int p = 0; p < c; p++) {
                float2 sj = s1d[ell_t[p * N_NODES + node]];
                float wj = sj.y * di;
                #pragma unroll
                for (int kk = 0; kk < 16; kk++)
                    ga[kk] += fmaxf(sj.x * w1r[kk] + b1r[kk], 0.f) * wj;
            }
        }
    }
    #pragma unroll
    for (int kk = 0; kk < 16; kk++) HsT[(grp * 16 + kk) * 32 + lane] = ga[kk];
    __syncthreads();

    // GEMM: 32 rows x 128 cols; each thread 4 rows x 4 cols
    int col = (t & 31) * 4;       // 0..124
    int row = (t >> 5) * 4;       // 0..28
    float a[4][4] = {};
    #pragma unroll 4
    for (int k = 0; k < 128; k++) {
        float4 w = *(const float4*)&W2[k * 128 + col];
        float4 h = *(float4*)&HsT[k * 32 + row];
        a[0][0] += h.x * w.x; a[0][1] += h.x * w.y; a[0][2] += h.x * w.z; a[0][3] += h.x * w.w;
        a[1][0] += h.y * w.x; a[1][1] += h.y * w.y; a[1][2] += h.y * w.z; a[1][3] += h.y * w.w;
        a[2][0] += h.z * w.x; a[2][1] += h.z * w.y; a[2][2] += h.z * w.z; a[2][3] += h.z * w.w;
        a[3][0] += h.w * w.x; a[3][1] += h.w * w.y; a[3][2] += h.w * w.z; a[3][3] += h.w * w.w;
    }

    // epilogue: relu(+b2), project to 2 outputs, reduce across 32 lanes, scale by dinv
    float b2r[4], w0r[4], w1rr[4];
    #pragma unroll
    for (int c = 0; c < 4; c++) {
        b2r[c] = b2[col + c];
        w0r[c] = w3buf[(col + c) * 2 + 0];
        w1rr[c] = w3buf[(col + c) * 2 + 1];
    }
    #pragma unroll
    for (int r = 0; r < 4; r++) {
        float p0 = 0.f, p1 = 0.f;
        #pragma unroll
        for (int c = 0; c < 4; c++) {
            float v0 = fmaxf(a[r][c] + b2r[c], 0.f);
            p0 += v0 * w0r[c];
            p1 += v0 * w1rr[c];
        }
        for (int o = 1; o < 32; o <<= 1) { p0 += __shfl_xor(p0, o); p1 += __shfl_xor(p1, o); }
        int rg = r0 + row + r;
        if ((t & 31) == 0 && rg < N_NODES) {
            float dr = s1d[rg].y;
            zd[rg * 2 + 0] = p0 * dr;
            zd[rg * 2 + 1] = p1 * dr;
        }
    }
}

// ---------------- Layer-3 aggregation on zd, 4 lanes/node, transposed reads -> az store ----

__global__ void k_aggz(const float* __restrict__ zd, const int* __restrict__ cnt,
                       const int* __restrict__ ell_t, const float* __restrict__ dinv,
                       float2* __restrict__ az) {
    int tid = blockIdx.x * 256 + threadIdx.x;
    int i = tid >> 2, sub = tid & 3;
    if (i >= N_NODES) return;
    const float2* Z = (const float2*)zd;
    int c = min(cnt[i], MAXDEG);
    float a0 = 0.f, a1 = 0.f;
    for (int p = sub; p < c; p += 4) {
        float2 zj = Z[ell_t[p * N_NODES + i]];
        a0 += zj.x; a1 += zj.y;
    }
    a0 += __shfl_xor(a0, 1); a1 += __shfl_xor(a1, 1);
    a0 += __shfl_xor(a0, 2); a1 += __shfl_xor(a1, 2);
    if (sub == 0) {
        float di = dinv[i];
        float2 zi = Z[i];
        float2 r = {(zi.x + a0) * di, (zi.y + a1) * di};   // zd_i*di + di*Σ zd_j
        az[i] = r;
    }
}

// ---------------- Final: one wave per graph — segment sum of az + mean + consts ----------------

__global__ __launch_bounds__(64) void k_final(const float2* __restrict__ az,
                                              const int* __restrict__ batch,
                                              const float* __restrict__ w3buf,
                                              float* __restrict__ out) {
    int g = blockIdx.x;
    int lane = threadIdx.x;
    int lo = 0, hi = N_NODES;
    while (lo < hi) { int mid = (lo + hi) >> 1; if (batch[mid] < g) lo = mid + 1; else hi = mid; }
    int start = lo;
    hi = N_NODES;
    while (lo < hi) { int mid = (lo + hi) >> 1; if (batch[mid] < g + 1) lo = mid + 1; else hi = mid; }
    int end = lo;
    float a0 = 0.f, a1 = 0.f;
    for (int n = start + lane; n < end; n += 64) {
        float2 v = az[n];
        a0 += v.x; a1 += v.y;
    }
    for (int o = 32; o; o >>= 1) { a0 += __shfl_xor(a0, o); a1 += __shfl_xor(a1, o); }
    if (lane == 0) {
        if (end > start) {
            float inv = 1.0f / (float)(end - start);
            out[g * 2 + 0] = a0 * inv + w3buf[256];
            out[g * 2 + 1] = a1 * inv + w3buf[257];
        } else {
            out[g * 2 + 0] = w3buf[258];
            out[g * 2 + 1] = w3buf[259];
        }
    }
}

// ---------------- launch ----------------

extern "C" void kernel_launch(void* const* d_in, const int* in_sizes, int n_in,
                              void* d_out, int out_size, void* d_ws, size_t ws_size,
                              hipStream_t stream) {
    const float* x    = (const float*)d_in[0];
    const float* W1   = (const float*)d_in[1];
    const float* b1   = (const float*)d_in[2];
    const float* W2   = (const float*)d_in[3];
    const float* b2   = (const float*)d_in[4];
    const float* W3   = (const float*)d_in[5];
    const float* b3   = (const float*)d_in[6];
    const float* Wlin = (const float*)d_in[7];
    const float* blin = (const float*)d_in[8];
    const int*   eidx = (const int*)d_in[9];
    const int*   batch= (const int*)d_in[10];
    const int* esrc = eidx;
    const int* edst = eidx + N_EDGES;
    float* out = (float*)d_out;

    char* w = (char*)d_ws;
    size_t off = 0;
    auto alloc = [&](size_t bytes) { size_t o = off; off = (off + bytes + 255) & ~(size_t)255; return o; };
    int*   cnt    = (int*)  (w + alloc(N_NODES * 4));
    int*   ell_t  = (int*)  (w + alloc((size_t)N_NODES * MAXDEG * 4));   // 9.6 MB, plane-major
    float* dinv   = (float*)(w + alloc(N_NODES * 4));
    float* xd     = (float*)(w + alloc(N_NODES * 4));
    float2* s1d   = (float2*)(w + alloc((size_t)N_NODES * 8));
    float* w3buf  = (float*)(w + alloc(260 * 4));
    float* zd     = (float*)(w + alloc((size_t)N_NODES * 2 * 4));
    float2* az    = (float2*)(w + alloc((size_t)N_NODES * 8));

    const int QB = (N_NODES * 4 + 255) / 256;   // 782 (4 lanes/node)
    // 1: zero cnt
    hipMemsetAsync(cnt, 0, N_NODES * 4, stream);
    // 2: transposed-ELL build (2 edges/thread) + w3lin precompute (extra block)
    k_ellfill<<<EB2, 256, 0, stream>>>(esrc, edst, cnt, ell_t, W3, Wlin, b3, blin, w3buf);
    // 3: dinv + xd
    k_nodeprep<<<NB_SCAN, 256, 0, stream>>>(cnt, x, dinv, xd);
    // 4: layer-1 scalar aggregate (4 lanes/node, plane-strided)
    k_s1d<<<QB, 256, 0, stream>>>(x, xd, dinv, cnt, ell_t, s1d);
    // 5: fused reconstruct + GEMM + relu + projection -> zd [N,2]  (coalesced plane staging)
    k_gemm_fused<<<(N_NODES + 31) / 32, 256, 0, stream>>>(s1d, cnt, ell_t,
                                                          W1, b1, W2, b2, w3buf, zd);
    // 6: layer-3 aggregation on zd (4 lanes/node, plane-strided) -> az
    k_aggz<<<QB, 256, 0, stream>>>(zd, cnt, ell_t, dinv, az);
    // 7: per-graph segment mean + consts (one wave per graph)
    k_final<<<NG, 64, 0, stream>>>(az, batch, w3buf, out);
}